// Round 2
// 881.002 us; speedup vs baseline: 1.0009x; 1.0009x over previous
//
#include <hip/hip_runtime.h>
#include <cstdint>
#include <cstddef>

#define D_MODEL 1024
#define D_FF    4096
#define NEXP    8
#define NTOK    8192
#define MAXT    136                 // max 128-row M-tiles across experts (<=135)
#define CAP     (MAXT * 128)        // 17408 padded rows capacity

typedef unsigned short ushort_t;
typedef __attribute__((ext_vector_type(8))) short   short8;
typedef __attribute__((ext_vector_type(4))) float   floatx4;
typedef __attribute__((ext_vector_type(4))) unsigned short ushort4v;

__device__ __forceinline__ ushort_t f2bf(float f) {
    union { float f; uint32_t u; } v; v.f = f;
    uint32_t r = v.u + 0x7fffu + ((v.u >> 16) & 1u);   // RNE
    return (ushort_t)(r >> 16);
}

__device__ __forceinline__ floatx4 mfma16(short8 a, short8 b, floatx4 c) {
    return __builtin_amdgcn_mfma_f32_16x16x32_bf16(a, b, c, 0, 0, 0);
}

// async global->LDS, 16B per lane; LDS dest is wave-uniform base + lane*16
__device__ __forceinline__ void gload16(const ushort_t* g, ushort_t* l) {
    __builtin_amdgcn_global_load_lds(
        (const __attribute__((address_space(1))) void*)g,
        (__attribute__((address_space(3))) void*)l, 16, 0, 0);
}

// decode padded-row tile id -> (expert, row0); returns 0 if past last tile
__device__ __forceinline__ int tile_decode(const int* __restrict__ counts,
                                           int tm, int& e_out, int& row0) {
    int cnts[NEXP];
#pragma unroll
    for (int e = 0; e < NEXP; ++e) cnts[e] = counts[e];   // independent loads
    int b = 0, t = tm;
#pragma unroll
    for (int e = 0; e < NEXP; ++e) {
        int nt = (cnts[e] + 127) >> 7;
        if (t < nt) { e_out = e; row0 = b + t * 128; return 1; }
        t -= nt; b += nt * 128;
    }
    return 0;
}

// ---------------------------------------------------------------- transpose+cvt (both weights, one dispatch)
// W1:[8][1024][4096] -> W1T:[8][4096][1024] bf16 ; W2:[8][4096][1024] -> W2T:[8][1024][4096] bf16
__global__ __launch_bounds__(256)
void transpose_all(const float* __restrict__ W1, const float* __restrict__ W2,
                   ushort_t* __restrict__ W1T, ushort_t* __restrict__ W2T)
{
    __shared__ float t[64][65];
    int bid = blockIdx.x;
    const float* in; ushort_t* out; int R, C, rt, ct;
    if (bid < 8192) {                       // W1 tiles: 16 r-tiles x 64 c-tiles per expert
        int e = bid >> 10, rem = bid & 1023;
        R = D_MODEL; C = D_FF; rt = rem >> 6; ct = rem & 63;
        in = W1 + (size_t)e * R * C; out = W1T + (size_t)e * R * C;
    } else {                                // W2 tiles: 64 r-tiles x 16 c-tiles per expert
        int e = (bid - 8192) >> 10, rem = bid & 1023;
        R = D_FF; C = D_MODEL; rt = rem >> 4; ct = rem & 15;
        in = W2 + (size_t)e * R * C; out = W2T + (size_t)e * R * C;
    }
    int r0 = rt * 64, c0 = ct * 64, tid = threadIdx.x;
    int lr = tid >> 4, lc4 = (tid & 15) * 4;
#pragma unroll
    for (int p = 0; p < 4; ++p) {
        int rr = p * 16 + lr;
        float4 v = *(const float4*)(in + (size_t)(r0 + rr) * C + c0 + lc4);
        t[rr][lc4] = v.x; t[rr][lc4 + 1] = v.y; t[rr][lc4 + 2] = v.z; t[rr][lc4 + 3] = v.w;
    }
    __syncthreads();
    int orw = tid >> 3, j0 = (tid & 7) * 8;
#pragma unroll
    for (int p = 0; p < 2; ++p) {
        int orow = p * 32 + orw;
        ushort_t pk[8];
#pragma unroll
        for (int i = 0; i < 8; ++i) pk[i] = f2bf(t[j0 + i][orow]);
        *(short8*)(out + (size_t)(c0 + orow) * R + r0 + j0) = *(short8*)pk;
    }
}

// ---------------------------------------------------------------- router
__global__ __launch_bounds__(256)
void router_kernel(const float* __restrict__ x, const float* __restrict__ Wg,
                   const float* __restrict__ bg,
                   int* __restrict__ counts, int* __restrict__ slot_tok,
                   float* __restrict__ slot_p, float* __restrict__ psum)
{
    __shared__ float bsum[NEXP];
    int tid = threadIdx.x;
    if (tid < NEXP) bsum[tid] = 0.f;
    __syncthreads();

    int t = (blockIdx.x * 256 + tid) >> 6;     // one wave per token
    int l = tid & 63;
    const float* xr = x + (size_t)t * D_MODEL;
    float acc[NEXP] = {0.f,0.f,0.f,0.f,0.f,0.f,0.f,0.f};
#pragma unroll 4
    for (int c = 0; c < D_MODEL / 64; ++c) {
        int d = c * 64 + l;
        float xv = xr[d];
        const float4* wr = (const float4*)(Wg + (size_t)d * NEXP);
        float4 w0 = wr[0], w1 = wr[1];
        acc[0] += xv * w0.x; acc[1] += xv * w0.y;
        acc[2] += xv * w0.z; acc[3] += xv * w0.w;
        acc[4] += xv * w1.x; acc[5] += xv * w1.y;
        acc[6] += xv * w1.z; acc[7] += xv * w1.w;
    }
#pragma unroll
    for (int off = 32; off >= 1; off >>= 1)
#pragma unroll
        for (int e = 0; e < NEXP; ++e)
            acc[e] += __shfl_xor(acc[e], off);

    if (l == 0) {
        float lg[NEXP], mx = -1e30f;
#pragma unroll
        for (int e = 0; e < NEXP; ++e) { lg[e] = acc[e] + bg[e]; mx = fmaxf(mx, lg[e]); }
        float pr[NEXP], s = 0.f;
#pragma unroll
        for (int e = 0; e < NEXP; ++e) { pr[e] = __expf(lg[e] - mx); s += pr[e]; }
        float inv = 1.f / s;
#pragma unroll
        for (int e = 0; e < NEXP; ++e) pr[e] *= inv;
        int e0 = 0;
#pragma unroll
        for (int e = 1; e < NEXP; ++e) if (pr[e] > pr[e0]) e0 = e;
        int e1 = (e0 == 0) ? 1 : 0;
#pragma unroll
        for (int e = 0; e < NEXP; ++e) if (e != e0 && pr[e] > pr[e1]) e1 = e;
        float pnorm = 1.f / (pr[e0] + pr[e1]);
        int s0 = atomicAdd(&counts[e0], 1);
        slot_tok[e0 * NTOK + s0] = t; slot_p[e0 * NTOK + s0] = pr[e0] * pnorm;
        int s1 = atomicAdd(&counts[e1], 1);
        slot_tok[e1 * NTOK + s1] = t; slot_p[e1 * NTOK + s1] = pr[e1] * pnorm;
#pragma unroll
        for (int e = 0; e < NEXP; ++e) atomicAdd(&bsum[e], pr[e]);
    }
    __syncthreads();
    if (tid < NEXP) atomicAdd(&psum[tid], bsum[tid]);
}

// ---------------------------------------------------------------- gather x -> xg (bf16)
__global__ __launch_bounds__(256)
void gather_kernel(const float* __restrict__ x, const int* __restrict__ counts,
                   const int* __restrict__ slot_tok, const float* __restrict__ slot_p,
                   ushort_t* __restrict__ xg, float* __restrict__ tok_prob,
                   int* __restrict__ tcount, int* __restrict__ tok2row)
{
    __shared__ int sb[NEXP + 1];
    int row = blockIdx.x, tid = threadIdx.x;
    if (tid == 0) {
        int b = 0;
#pragma unroll
        for (int e = 0; e < NEXP; ++e) { sb[e] = b; b += ((counts[e] + 127) >> 7) << 7; }
        sb[NEXP] = b;
    }
    __syncthreads();
    if (row >= sb[NEXP]) return;
    int e = 0;
    while (e < NEXP - 1 && row >= sb[e + 1]) ++e;
    int lr = row - sb[e];
    int tok = -1; float pr = 0.f;
    if (lr < counts[e]) { tok = slot_tok[e * NTOK + lr]; pr = slot_p[e * NTOK + lr]; }
    if (tid == 0) {
        tok_prob[row] = pr;
        if (tok >= 0) {
            int s = atomicAdd(&tcount[tok], 1);   // 0 or 1
            tok2row[tok * 2 + s] = row;
        }
    }
    ushort_t* dst = xg + (size_t)row * D_MODEL;
    if (tok >= 0) {
        float4 v = ((const float4*)(x + (size_t)tok * D_MODEL))[tid];
        ushort4v o; o.x = f2bf(v.x); o.y = f2bf(v.y); o.z = f2bf(v.z); o.w = f2bf(v.w);
        *(ushort4v*)(dst + tid * 4) = o;
    } else {
        *(ushort4v*)(dst + tid * 4) = ushort4v{0, 0, 0, 0};
    }
}

// ---------------------------------------------------------------- grouped GEMM
// C[128x128] = A[tile rows][K] * B[e][colbase..+128][K]^T  (both bf16, k-contig)
// m97 structure: single 32KB LDS buffer, async global_load_lds_dwordx4 staging,
// 2 barriers per K-step (measured 874-912 TF at this tile in learn_hip m97/m103
// vs 646 TF reg-staged, m151). XOR chunk swizzle kept conflict-free by
// PRE-SWIZZLING the per-lane global source (linear LDS dest + inverse-swizzled
// src + swizzled read — both-sides-or-neither rule). XCD chunk swizzle (T1,
// bijective: nwg%8==0 for both grids) in front of 4x4 supertile for L2 reuse.
// EPI 0: h = relu(C + b1) -> bf16 Hout (single-barrier 32KB LDS epilogue)
// EPI 1: Yout[row] = C + b2 (f32, direct stores; combined later)
template <int EPI>
__global__ __launch_bounds__(256, 2)
void gemm_tile(const ushort_t* __restrict__ A, const ushort_t* __restrict__ B,
               int K, int N, const int* __restrict__ counts,
               int row_lo, int row_hi,
               ushort_t* __restrict__ Hout, const float* __restrict__ bias,
               float* __restrict__ Yout)
{
    // ---- XCD chunk (T1) then 4x4 super-tile: 16 consecutive = 4 cols x 4 tiles
    int NX = gridDim.x;
    int nwg = NX * (int)gridDim.y;           // 1088 or 4352, both %8==0
    int lin0 = blockIdx.y * NX + blockIdx.x;
    int cpx = nwg >> 3;
    int lin = (lin0 & 7) * cpx + (lin0 >> 3);
    int sid = lin >> 4, wi = lin & 15;
    int nsx = NX >> 2;
    int sx = sid % nsx, sy = sid / nsx;
    int colbase = ((sx << 2) + (wi & 3)) * 128;
    int tm = (sy << 2) + (wi >> 2);

    int e, row0;
    if (!tile_decode(counts, tm, e, row0)) return;
    if (row0 < row_lo || row0 >= row_hi) return;

    __shared__ ushort_t smem[128 * 64 * 2];      // As 16KB | Bs 16KB
    ushort_t* As = smem;
    ushort_t* Bs = smem + 128 * 64;

    int tid = threadIdx.x;
    int w = tid >> 6, l = tid & 63;
    int q = l >> 4, ml = l & 15;
    int wm = w >> 1, wn = w & 1;

    const ushort_t* Ab = A + (size_t)row0 * K;
    const ushort_t* Bb = B + ((size_t)e * N + colbase) * K;

    // staging geometry: issue i of wave w covers LDS rows [(i*4+w)*8, +8)
    // linearly (1KB). LDS (r, chunk c) must hold global chunk (c ^ (r&7)).
    const ushort_t* ag[4]; const ushort_t* bg[4];
    ushort_t* al[4]; ushort_t* bl[4];
#pragma unroll
    for (int i = 0; i < 4; ++i) {
        int rr = (i * 4 + w) * 8 + (l >> 3);
        int cc = ((l & 7) ^ (rr & 7)) * 8;       // pre-swizzled source chunk
        ag[i] = Ab + (size_t)rr * K + cc;
        bg[i] = Bb + (size_t)rr * K + cc;
        al[i] = As + (i * 4 + w) * 512;          // wave-uniform dest base
        bl[i] = Bs + (i * 4 + w) * 512;
    }

    floatx4 acc[4][4];
#pragma unroll
    for (int i = 0; i < 4; ++i)
#pragma unroll
        for (int j = 0; j < 4; ++j) acc[i][j] = floatx4{0.f, 0.f, 0.f, 0.f};

    int nst = K >> 6;
    for (int s = 0; s < nst; ++s) {
#pragma unroll
        for (int i = 0; i < 4; ++i) {            // 8 x global_load_lds_dwordx4
            gload16(ag[i], al[i]);
            gload16(bg[i], bl[i]);
            ag[i] += 64; bg[i] += 64;
        }
        __syncthreads();                          // vmcnt(0) drain + barrier
#pragma unroll
        for (int kk = 0; kk < 2; ++kk) {
            int cb = kk * 4 + q;
            short8 av[4], bv[4];
#pragma unroll
            for (int mi = 0; mi < 4; ++mi) {
                int m = wm * 64 + mi * 16 + ml;
                av[mi] = *(const short8*)(As + m * 64 + ((cb ^ (m & 7)) * 8));
            }
#pragma unroll
            for (int ni = 0; ni < 4; ++ni) {
                int n = wn * 64 + ni * 16 + ml;
                bv[ni] = *(const short8*)(Bs + n * 64 + ((cb ^ (n & 7)) * 8));
            }
#pragma unroll
            for (int mi = 0; mi < 4; ++mi)
#pragma unroll
                for (int ni = 0; ni < 4; ++ni)
                    acc[mi][ni] = mfma16(av[mi], bv[ni], acc[mi][ni]);
        }
        __syncthreads();                          // reads done before next stage
    }

    float bv4[4];
#pragma unroll
    for (int ni = 0; ni < 4; ++ni)
        bv4[ni] = bias[e * N + colbase + wn * 64 + ni * 16 + ml];

    if (EPI == 0) {
        // single-barrier epilogue: full 128x128 bf16 tile in the 32KB smem
        ushort_t* ct = smem;
#pragma unroll
        for (int mi = 0; mi < 4; ++mi)
#pragma unroll
            for (int ni = 0; ni < 4; ++ni)
#pragma unroll
                for (int r = 0; r < 4; ++r) {
                    float v = acc[mi][ni][r] + bv4[ni];
                    v = v > 0.f ? v : 0.f;
                    ct[(wm * 64 + mi * 16 + q * 4 + r) * 128 + wn * 64 + ni * 16 + ml] = f2bf(v);
                }
        __syncthreads();
#pragma unroll
        for (int i = 0; i < 8; ++i) {
            int idx = tid + i * 256;             // 2048 chunks of 16B
            int r = idx >> 4, c8 = idx & 15;
            *(short8*)(Hout + (size_t)(row0 + r) * D_FF + colbase + c8 * 8) =
                *(const short8*)(ct + r * 128 + c8 * 8);
        }
    } else {
#pragma unroll
        for (int mi = 0; mi < 4; ++mi)
#pragma unroll
            for (int ni = 0; ni < 4; ++ni)
#pragma unroll
                for (int r = 0; r < 4; ++r) {
                    int row = row0 + wm * 64 + mi * 16 + q * 4 + r;
                    int col = colbase + wn * 64 + ni * 16 + ml;
                    Yout[(size_t)row * N + col] = acc[mi][ni][r] + bv4[ni];
                }
    }
}

// ---------------------------------------------------------------- combine (+loss)
__global__ __launch_bounds__(256)
void combine_kernel(const float* __restrict__ y, const int* __restrict__ tok2row,
                    const float* __restrict__ tok_prob, float* __restrict__ out,
                    const float* __restrict__ psum, float* __restrict__ loss_out)
{
    int t = blockIdx.x;
    if (t == 0 && threadIdx.x == 0) {
        float me[NEXP], m = 0.f;
#pragma unroll
        for (int e = 0; e < NEXP; ++e) { me[e] = psum[e] * (1.f / NTOK); m += me[e] * (1.f / NEXP); }
        float v = 0.f;
#pragma unroll
        for (int e = 0; e < NEXP; ++e) v += (me[e] - m) * (me[e] - m);
        loss_out[0] = v * (1.f / (NEXP - 1));
    }
    int r0 = tok2row[t * 2], r1 = tok2row[t * 2 + 1];
    float p0 = tok_prob[r0], p1 = tok_prob[r1];
    int c = threadIdx.x;
    float4 a = ((const float4*)(y + (size_t)r0 * D_MODEL))[c];
    float4 b = ((const float4*)(y + (size_t)r1 * D_MODEL))[c];
    float4 o;
    o.x = p0 * a.x + p1 * b.x;
    o.y = p0 * a.y + p1 * b.y;
    o.z = p0 * a.z + p1 * b.z;
    o.w = p0 * a.w + p1 * b.w;
    ((float4*)(out + (size_t)t * D_MODEL))[c] = o;
}

// ---------------------------------------------------------------- launch
extern "C" void kernel_launch(void* const* d_in, const int* in_sizes, int n_in,
                              void* d_out, int out_size, void* d_ws, size_t ws_size,
                              hipStream_t stream)
{
    const float* x  = (const float*)d_in[0];
    const float* Wg = (const float*)d_in[1];
    const float* bg = (const float*)d_in[2];
    const float* W1 = (const float*)d_in[3];
    const float* b1 = (const float*)d_in[4];
    const float* W2 = (const float*)d_in[5];
    const float* b2 = (const float*)d_in[6];
    float* out = (float*)d_out;

    char* ws = (char*)d_ws;
    size_t off = 0;
    auto alloc = [&](size_t bytes) -> char* {
        char* p = ws + off;
        off = (off + bytes + 255) & ~(size_t)255;
        return p;
    };
    // zero-initialized region first (one memset covers it)
    int*      counts   = (int*)alloc(NEXP * 4);
    float*    psum     = (float*)alloc(NEXP * 4);
    int*      tcount   = (int*)alloc(NTOK * 4);
    size_t zero_bytes = off;
    // rest
    float*    tok_prob = (float*)alloc(CAP * 4);
    int*      tok2row  = (int*)alloc((size_t)NTOK * 2 * 4);
    int*      slot_tok = (int*)alloc((size_t)NEXP * NTOK * 4);
    float*    slot_p   = (float*)alloc((size_t)NEXP * NTOK * 4);
    ushort_t* xg       = (ushort_t*)alloc((size_t)CAP * D_MODEL * 2);
    ushort_t* W1T      = (ushort_t*)alloc((size_t)NEXP * D_MODEL * D_FF * 2);
    ushort_t* W2T      = (ushort_t*)alloc((size_t)NEXP * D_MODEL * D_FF * 2);
    float*    ybuf     = (float*)alloc((size_t)CAP * D_MODEL * 4);
    size_t fixed = off;
    size_t h_full = (size_t)CAP * D_FF * 2;

    int NC = 1;                                    // chunk h if ws is small
    if (ws_size < fixed + h_full) NC = 4;
    if (NC == 4 && ws_size < fixed + h_full / 4) NC = 16;
    if (ws_size < fixed + h_full / NC) return;     // cannot run safely
    int chunk_rows = CAP / NC;
    ushort_t* hbuf = (ushort_t*)alloc(h_full / NC);

    hipMemsetAsync(d_ws, 0, zero_bytes, stream);   // counts + psum + tcount

    transpose_all<<<16384, 256, 0, stream>>>(W1, W2, W1T, W2T);
    router_kernel<<<NTOK / 4, 256, 0, stream>>>(x, Wg, bg, counts, slot_tok, slot_p, psum);
    gather_kernel<<<CAP, 256, 0, stream>>>(x, counts, slot_tok, slot_p, xg,
                                           tok_prob, tcount, tok2row);
    for (int c = 0; c < NC; ++c) {
        int lo = c * chunk_rows, hi = lo + chunk_rows;
        ushort_t* h_eff = hbuf - (ptrdiff_t)lo * D_FF;   // abs-row indexed view
        gemm_tile<0><<<dim3(D_FF / 128, MAXT), 256, 0, stream>>>(
            xg, W1T, D_MODEL, D_FF, counts, lo, hi, h_eff, b1, nullptr);
        gemm_tile<1><<<dim3(D_MODEL / 128, MAXT), 256, 0, stream>>>(
            h_eff, W2T, D_FF, D_MODEL, counts, lo, hi, nullptr, b2, ybuf);
    }
    combine_kernel<<<NTOK, 256, 0, stream>>>(ybuf, tok2row, tok_prob, out, psum,
                                             out + (size_t)out_size - 1);
    (void)in_sizes; (void)n_in;
}

// Round 3
// 879.763 us; speedup vs baseline: 1.0023x; 1.0014x over previous
//
#include <hip/hip_runtime.h>
#include <cstdint>
#include <cstddef>

#define D_MODEL 1024
#define D_FF    4096
#define NEXP    8
#define NTOK    8192
#define MAXT    136                 // max 128-row M-tiles across experts (<=135)
#define CAP     (MAXT * 128)        // 17408 padded rows capacity

typedef unsigned short ushort_t;
typedef __attribute__((ext_vector_type(8))) short   short8;
typedef __attribute__((ext_vector_type(4))) float   floatx4;
typedef __attribute__((ext_vector_type(4))) unsigned short ushort4v;

__device__ __forceinline__ ushort_t f2bf(float f) {
    union { float f; uint32_t u; } v; v.f = f;
    uint32_t r = v.u + 0x7fffu + ((v.u >> 16) & 1u);   // RNE
    return (ushort_t)(r >> 16);
}

__device__ __forceinline__ floatx4 mfma16(short8 a, short8 b, floatx4 c) {
    return __builtin_amdgcn_mfma_f32_16x16x32_bf16(a, b, c, 0, 0, 0);
}

// async global->LDS, 16B per lane; LDS dest is wave-uniform base + lane*16
__device__ __forceinline__ void gload16(const ushort_t* g, ushort_t* l) {
    __builtin_amdgcn_global_load_lds(
        (const __attribute__((address_space(1))) void*)g,
        (__attribute__((address_space(3))) void*)l, 16, 0, 0);
}

// decode padded-row tile id -> (expert, row0); returns 0 if past last tile
__device__ __forceinline__ int tile_decode(const int* __restrict__ counts,
                                           int tm, int& e_out, int& row0) {
    int cnts[NEXP];
#pragma unroll
    for (int e = 0; e < NEXP; ++e) cnts[e] = counts[e];   // independent loads
    int b = 0, t = tm;
#pragma unroll
    for (int e = 0; e < NEXP; ++e) {
        int nt = (cnts[e] + 127) >> 7;
        if (t < nt) { e_out = e; row0 = b + t * 128; return 1; }
        t -= nt; b += nt * 128;
    }
    return 0;
}

// ---------------------------------------------------------------- transpose+cvt (both weights, one dispatch)
// W1:[8][1024][4096] -> W1T:[8][4096][1024] bf16 ; W2:[8][4096][1024] -> W2T:[8][1024][4096] bf16
__global__ __launch_bounds__(256)
void transpose_all(const float* __restrict__ W1, const float* __restrict__ W2,
                   ushort_t* __restrict__ W1T, ushort_t* __restrict__ W2T)
{
    __shared__ float t[64][65];
    int bid = blockIdx.x;
    const float* in; ushort_t* out; int R, C, rt, ct;
    if (bid < 8192) {                       // W1 tiles: 16 r-tiles x 64 c-tiles per expert
        int e = bid >> 10, rem = bid & 1023;
        R = D_MODEL; C = D_FF; rt = rem >> 6; ct = rem & 63;
        in = W1 + (size_t)e * R * C; out = W1T + (size_t)e * R * C;
    } else {                                // W2 tiles: 64 r-tiles x 16 c-tiles per expert
        int e = (bid - 8192) >> 10, rem = bid & 1023;
        R = D_FF; C = D_MODEL; rt = rem >> 4; ct = rem & 15;
        in = W2 + (size_t)e * R * C; out = W2T + (size_t)e * R * C;
    }
    int r0 = rt * 64, c0 = ct * 64, tid = threadIdx.x;
    int lr = tid >> 4, lc4 = (tid & 15) * 4;
#pragma unroll
    for (int p = 0; p < 4; ++p) {
        int rr = p * 16 + lr;
        float4 v = *(const float4*)(in + (size_t)(r0 + rr) * C + c0 + lc4);
        t[rr][lc4] = v.x; t[rr][lc4 + 1] = v.y; t[rr][lc4 + 2] = v.z; t[rr][lc4 + 3] = v.w;
    }
    __syncthreads();
    int orw = tid >> 3, j0 = (tid & 7) * 8;
#pragma unroll
    for (int p = 0; p < 2; ++p) {
        int orow = p * 32 + orw;
        ushort_t pk[8];
#pragma unroll
        for (int i = 0; i < 8; ++i) pk[i] = f2bf(t[j0 + i][orow]);
        *(short8*)(out + (size_t)(c0 + orow) * R + r0 + j0) = *(short8*)pk;
    }
}

// ---------------------------------------------------------------- router
__global__ __launch_bounds__(256)
void router_kernel(const float* __restrict__ x, const float* __restrict__ Wg,
                   const float* __restrict__ bg,
                   int* __restrict__ counts, int* __restrict__ slot_tok,
                   float* __restrict__ slot_p, float* __restrict__ psum)
{
    __shared__ float bsum[NEXP];
    int tid = threadIdx.x;
    if (tid < NEXP) bsum[tid] = 0.f;
    __syncthreads();

    int t = (blockIdx.x * 256 + tid) >> 6;     // one wave per token
    int l = tid & 63;
    const float* xr = x + (size_t)t * D_MODEL;
    float acc[NEXP] = {0.f,0.f,0.f,0.f,0.f,0.f,0.f,0.f};
#pragma unroll 4
    for (int c = 0; c < D_MODEL / 64; ++c) {
        int d = c * 64 + l;
        float xv = xr[d];
        const float4* wr = (const float4*)(Wg + (size_t)d * NEXP);
        float4 w0 = wr[0], w1 = wr[1];
        acc[0] += xv * w0.x; acc[1] += xv * w0.y;
        acc[2] += xv * w0.z; acc[3] += xv * w0.w;
        acc[4] += xv * w1.x; acc[5] += xv * w1.y;
        acc[6] += xv * w1.z; acc[7] += xv * w1.w;
    }
#pragma unroll
    for (int off = 32; off >= 1; off >>= 1)
#pragma unroll
        for (int e = 0; e < NEXP; ++e)
            acc[e] += __shfl_xor(acc[e], off);

    if (l == 0) {
        float lg[NEXP], mx = -1e30f;
#pragma unroll
        for (int e = 0; e < NEXP; ++e) { lg[e] = acc[e] + bg[e]; mx = fmaxf(mx, lg[e]); }
        float pr[NEXP], s = 0.f;
#pragma unroll
        for (int e = 0; e < NEXP; ++e) { pr[e] = __expf(lg[e] - mx); s += pr[e]; }
        float inv = 1.f / s;
#pragma unroll
        for (int e = 0; e < NEXP; ++e) pr[e] *= inv;
        int e0 = 0;
#pragma unroll
        for (int e = 1; e < NEXP; ++e) if (pr[e] > pr[e0]) e0 = e;
        int e1 = (e0 == 0) ? 1 : 0;
#pragma unroll
        for (int e = 0; e < NEXP; ++e) if (e != e0 && pr[e] > pr[e1]) e1 = e;
        float pnorm = 1.f / (pr[e0] + pr[e1]);
        int s0 = atomicAdd(&counts[e0], 1);
        slot_tok[e0 * NTOK + s0] = t; slot_p[e0 * NTOK + s0] = pr[e0] * pnorm;
        int s1 = atomicAdd(&counts[e1], 1);
        slot_tok[e1 * NTOK + s1] = t; slot_p[e1 * NTOK + s1] = pr[e1] * pnorm;
#pragma unroll
        for (int e = 0; e < NEXP; ++e) atomicAdd(&bsum[e], pr[e]);
    }
    __syncthreads();
    if (tid < NEXP) atomicAdd(&psum[tid], bsum[tid]);
}

// ---------------------------------------------------------------- gather x -> xg (bf16)
__global__ __launch_bounds__(256)
void gather_kernel(const float* __restrict__ x, const int* __restrict__ counts,
                   const int* __restrict__ slot_tok, const float* __restrict__ slot_p,
                   ushort_t* __restrict__ xg, float* __restrict__ tok_prob,
                   int* __restrict__ tcount, int* __restrict__ tok2row)
{
    __shared__ int sb[NEXP + 1];
    int row = blockIdx.x, tid = threadIdx.x;
    if (tid == 0) {
        int b = 0;
#pragma unroll
        for (int e = 0; e < NEXP; ++e) { sb[e] = b; b += ((counts[e] + 127) >> 7) << 7; }
        sb[NEXP] = b;
    }
    __syncthreads();
    if (row >= sb[NEXP]) return;
    int e = 0;
    while (e < NEXP - 1 && row >= sb[e + 1]) ++e;
    int lr = row - sb[e];
    int tok = -1; float pr = 0.f;
    if (lr < counts[e]) { tok = slot_tok[e * NTOK + lr]; pr = slot_p[e * NTOK + lr]; }
    if (tid == 0) {
        tok_prob[row] = pr;
        if (tok >= 0) {
            int s = atomicAdd(&tcount[tok], 1);   // 0 or 1
            tok2row[tok * 2 + s] = row;
        }
    }
    ushort_t* dst = xg + (size_t)row * D_MODEL;
    if (tok >= 0) {
        float4 v = ((const float4*)(x + (size_t)tok * D_MODEL))[tid];
        ushort4v o; o.x = f2bf(v.x); o.y = f2bf(v.y); o.z = f2bf(v.z); o.w = f2bf(v.w);
        *(ushort4v*)(dst + tid * 4) = o;
    } else {
        *(ushort4v*)(dst + tid * 4) = ushort4v{0, 0, 0, 0};
    }
}

// ---------------------------------------------------------------- grouped GEMM
// C[128x128] = A[tile rows][K] * B[e][colbase..+128][K]^T  (both bf16, k-contig)
// 2-phase double-buffered pipeline (catalog T3-minimum + T4 counted vmcnt):
//   iter s: issue 8 global_load_lds -> buf[p^1]; s_waitcnt vmcnt(8) (waits
//   ONLY the previous tile's loads -- the new 8 stay in flight across the
//   barrier, m135/m218 mechanism); raw s_barrier; MFMA on buf[p]; raw
//   s_barrier. Both barriers MUST be raw s_barrier: __syncthreads() would
//   re-insert vmcnt(0) and drain the prefetch (the measured ~60%-idle stall).
// XOR chunk swizzle conflict-free via pre-swizzled global source (rule #21).
// XCD chunk swizzle (T1, bijective: nwg%8==0 for both grids) for L2 reuse
// (verified: FETCH 423->200 MB).
// EPI 0: h = relu(C + b1) -> bf16 Hout (single-barrier 32KB LDS epilogue)
// EPI 1: Yout[row] = C + b2 (f32, direct stores; combined later)
template <int EPI>
__global__ __launch_bounds__(256, 2)
void gemm_tile(const ushort_t* __restrict__ A, const ushort_t* __restrict__ B,
               int K, int N, const int* __restrict__ counts,
               int row_lo, int row_hi,
               ushort_t* __restrict__ Hout, const float* __restrict__ bias,
               float* __restrict__ Yout)
{
    // ---- XCD chunk (T1) then 4x4 super-tile: 16 consecutive = 4 cols x 4 tiles
    int NX = gridDim.x;
    int nwg = NX * (int)gridDim.y;           // 1088 or 4352, both %8==0
    int lin0 = blockIdx.y * NX + blockIdx.x;
    int cpx = nwg >> 3;
    int lin = (lin0 & 7) * cpx + (lin0 >> 3);
    int sid = lin >> 4, wi = lin & 15;
    int nsx = NX >> 2;
    int sx = sid % nsx, sy = sid / nsx;
    int colbase = ((sx << 2) + (wi & 3)) * 128;
    int tm = (sy << 2) + (wi >> 2);

    int e, row0;
    if (!tile_decode(counts, tm, e, row0)) return;
    if (row0 < row_lo || row0 >= row_hi) return;

    // double buffer: buf p at smem + p*16384 elems (As 16KB | Bs 16KB each)
    __shared__ ushort_t smem[128 * 64 * 2 * 2];  // 64 KB

    int tid = threadIdx.x;
    int w = tid >> 6, l = tid & 63;
    int q = l >> 4, ml = l & 15;
    int wm = w >> 1, wn = w & 1;

    const ushort_t* Ab = A + (size_t)row0 * K;
    const ushort_t* Bb = B + ((size_t)e * N + colbase) * K;

    // staging geometry: issue i of wave w covers LDS rows [(i*4+w)*8, +8)
    // linearly (1KB). LDS (r, chunk c) must hold global chunk (c ^ (r&7)).
    const ushort_t* ag[4]; const ushort_t* bg[4];
    int lofs[4];
#pragma unroll
    for (int i = 0; i < 4; ++i) {
        int rr = (i * 4 + w) * 8 + (l >> 3);
        int cc = ((l & 7) ^ (rr & 7)) * 8;       // pre-swizzled source chunk
        ag[i] = Ab + (size_t)rr * K + cc;
        bg[i] = Bb + (size_t)rr * K + cc;
        lofs[i] = (i * 4 + w) * 512;             // wave-uniform dest base (elems)
    }

#define STAGE(p)                                                           \
    do {                                                                   \
        ushort_t* base_ = smem + (p) * 16384;                              \
        _Pragma("unroll")                                                  \
        for (int i_ = 0; i_ < 4; ++i_) {                                   \
            gload16(ag[i_], base_ + lofs[i_]);                             \
            gload16(bg[i_], base_ + 8192 + lofs[i_]);                      \
            ag[i_] += 64; bg[i_] += 64;                                    \
        }                                                                  \
    } while (0)

    floatx4 acc[4][4];
#pragma unroll
    for (int i = 0; i < 4; ++i)
#pragma unroll
        for (int j = 0; j < 4; ++j) acc[i][j] = floatx4{0.f, 0.f, 0.f, 0.f};

    int nst = K >> 6;
    STAGE(0);                                    // prologue: tile 0 in flight
    for (int s = 0; s < nst; ++s) {
        int p = s & 1;
        if (s + 1 < nst) {
            STAGE(p ^ 1);                        // next tile: stays in flight
            asm volatile("s_waitcnt vmcnt(8)" ::: "memory");   // prev 8 done
        } else {
            asm volatile("s_waitcnt vmcnt(0)" ::: "memory");
        }
        __builtin_amdgcn_s_barrier();            // buf[p] collectively ready
        __builtin_amdgcn_sched_barrier(0);       // keep ds_reads below waits
        const ushort_t* As = smem + p * 16384;
        const ushort_t* Bs = As + 8192;
#pragma unroll
        for (int kk = 0; kk < 2; ++kk) {
            int cb = kk * 4 + q;
            short8 av[4], bv[4];
#pragma unroll
            for (int mi = 0; mi < 4; ++mi) {
                int m = wm * 64 + mi * 16 + ml;
                av[mi] = *(const short8*)(As + m * 64 + ((cb ^ (m & 7)) * 8));
            }
#pragma unroll
            for (int ni = 0; ni < 4; ++ni) {
                int n = wn * 64 + ni * 16 + ml;
                bv[ni] = *(const short8*)(Bs + n * 64 + ((cb ^ (n & 7)) * 8));
            }
#pragma unroll
            for (int mi = 0; mi < 4; ++mi)
#pragma unroll
                for (int ni = 0; ni < 4; ++ni)
                    acc[mi][ni] = mfma16(av[mi], bv[ni], acc[mi][ni]);
        }
        __builtin_amdgcn_s_barrier();            // reads done before overwrite
    }
#undef STAGE

    float bv4[4];
#pragma unroll
    for (int ni = 0; ni < 4; ++ni)
        bv4[ni] = bias[e * N + colbase + wn * 64 + ni * 16 + ml];

    if (EPI == 0) {
        // single-barrier epilogue: full 128x128 bf16 tile in smem buf0
        ushort_t* ct = smem;
#pragma unroll
        for (int mi = 0; mi < 4; ++mi)
#pragma unroll
            for (int ni = 0; ni < 4; ++ni)
#pragma unroll
                for (int r = 0; r < 4; ++r) {
                    float v = acc[mi][ni][r] + bv4[ni];
                    v = v > 0.f ? v : 0.f;
                    ct[(wm * 64 + mi * 16 + q * 4 + r) * 128 + wn * 64 + ni * 16 + ml] = f2bf(v);
                }
        __syncthreads();
#pragma unroll
        for (int i = 0; i < 8; ++i) {
            int idx = tid + i * 256;             // 2048 chunks of 16B
            int r = idx >> 4, c8 = idx & 15;
            *(short8*)(Hout + (size_t)(row0 + r) * D_FF + colbase + c8 * 8) =
                *(const short8*)(ct + r * 128 + c8 * 8);
        }
    } else {
#pragma unroll
        for (int mi = 0; mi < 4; ++mi)
#pragma unroll
            for (int ni = 0; ni < 4; ++ni)
#pragma unroll
                for (int r = 0; r < 4; ++r) {
                    int row = row0 + wm * 64 + mi * 16 + q * 4 + r;
                    int col = colbase + wn * 64 + ni * 16 + ml;
                    Yout[(size_t)row * N + col] = acc[mi][ni][r] + bv4[ni];
                }
    }
}

// ---------------------------------------------------------------- combine (+loss)
__global__ __launch_bounds__(256)
void combine_kernel(const float* __restrict__ y, const int* __restrict__ tok2row,
                    const float* __restrict__ tok_prob, float* __restrict__ out,
                    const float* __restrict__ psum, float* __restrict__ loss_out)
{
    int t = blockIdx.x;
    if (t == 0 && threadIdx.x == 0) {
        float me[NEXP], m = 0.f;
#pragma unroll
        for (int e = 0; e < NEXP; ++e) { me[e] = psum[e] * (1.f / NTOK); m += me[e] * (1.f / NEXP); }
        float v = 0.f;
#pragma unroll
        for (int e = 0; e < NEXP; ++e) v += (me[e] - m) * (me[e] - m);
        loss_out[0] = v * (1.f / (NEXP - 1));
    }
    int r0 = tok2row[t * 2], r1 = tok2row[t * 2 + 1];
    float p0 = tok_prob[r0], p1 = tok_prob[r1];
    int c = threadIdx.x;
    float4 a = ((const float4*)(y + (size_t)r0 * D_MODEL))[c];
    float4 b = ((const float4*)(y + (size_t)r1 * D_MODEL))[c];
    float4 o;
    o.x = p0 * a.x + p1 * b.x;
    o.y = p0 * a.y + p1 * b.y;
    o.z = p0 * a.z + p1 * b.z;
    o.w = p0 * a.w + p1 * b.w;
    ((float4*)(out + (size_t)t * D_MODEL))[c] = o;
}

// ---------------------------------------------------------------- launch
extern "C" void kernel_launch(void* const* d_in, const int* in_sizes, int n_in,
                              void* d_out, int out_size, void* d_ws, size_t ws_size,
                              hipStream_t stream)
{
    const float* x  = (const float*)d_in[0];
    const float* Wg = (const float*)d_in[1];
    const float* bg = (const float*)d_in[2];
    const float* W1 = (const float*)d_in[3];
    const float* b1 = (const float*)d_in[4];
    const float* W2 = (const float*)d_in[5];
    const float* b2 = (const float*)d_in[6];
    float* out = (float*)d_out;

    char* ws = (char*)d_ws;
    size_t off = 0;
    auto alloc = [&](size_t bytes) -> char* {
        char* p = ws + off;
        off = (off + bytes + 255) & ~(size_t)255;
        return p;
    };
    // zero-initialized region first (one memset covers it)
    int*      counts   = (int*)alloc(NEXP * 4);
    float*    psum     = (float*)alloc(NEXP * 4);
    int*      tcount   = (int*)alloc(NTOK * 4);
    size_t zero_bytes = off;
    // rest
    float*    tok_prob = (float*)alloc(CAP * 4);
    int*      tok2row  = (int*)alloc((size_t)NTOK * 2 * 4);
    int*      slot_tok = (int*)alloc((size_t)NEXP * NTOK * 4);
    float*    slot_p   = (float*)alloc((size_t)NEXP * NTOK * 4);
    ushort_t* xg       = (ushort_t*)alloc((size_t)CAP * D_MODEL * 2);
    ushort_t* W1T      = (ushort_t*)alloc((size_t)NEXP * D_MODEL * D_FF * 2);
    ushort_t* W2T      = (ushort_t*)alloc((size_t)NEXP * D_MODEL * D_FF * 2);
    float*    ybuf     = (float*)alloc((size_t)CAP * D_MODEL * 4);
    size_t fixed = off;
    size_t h_full = (size_t)CAP * D_FF * 2;

    int NC = 1;                                    // chunk h if ws is small
    if (ws_size < fixed + h_full) NC = 4;
    if (NC == 4 && ws_size < fixed + h_full / 4) NC = 16;
    if (ws_size < fixed + h_full / NC) return;     // cannot run safely
    int chunk_rows = CAP / NC;
    ushort_t* hbuf = (ushort_t*)alloc(h_full / NC);

    hipMemsetAsync(d_ws, 0, zero_bytes, stream);   // counts + psum + tcount

    transpose_all<<<16384, 256, 0, stream>>>(W1, W2, W1T, W2T);
    router_kernel<<<NTOK / 4, 256, 0, stream>>>(x, Wg, bg, counts, slot_tok, slot_p, psum);
    gather_kernel<<<CAP, 256, 0, stream>>>(x, counts, slot_tok, slot_p, xg,
                                           tok_prob, tcount, tok2row);
    for (int c = 0; c < NC; ++c) {
        int lo = c * chunk_rows, hi = lo + chunk_rows;
        ushort_t* h_eff = hbuf - (ptrdiff_t)lo * D_FF;   // abs-row indexed view
        gemm_tile<0><<<dim3(D_FF / 128, MAXT), 256, 0, stream>>>(
            xg, W1T, D_MODEL, D_FF, counts, lo, hi, h_eff, b1, nullptr);
        gemm_tile<1><<<dim3(D_MODEL / 128, MAXT), 256, 0, stream>>>(
            h_eff, W2T, D_FF, D_MODEL, counts, lo, hi, nullptr, b2, ybuf);
    }
    combine_kernel<<<NTOK, 256, 0, stream>>>(ybuf, tok2row, tok_prob, out, psum,
                                             out + (size_t)out_size - 1);
    (void)in_sizes; (void)n_in;
}

// Round 5
// 731.790 us; speedup vs baseline: 1.2050x; 1.2022x over previous
//
#include <hip/hip_runtime.h>
#include <cstdint>
#include <cstddef>

#define D_MODEL 1024
#define D_FF    4096
#define NEXP    8
#define NTOK    8192
#define MAXT    136                 // max 128-row M-tiles across experts (<=135)
#define CAP     (MAXT * 128)        // 17408 padded rows capacity
#define RBLK    (NTOK / 4)          // router blocks (wave-per-token)

typedef unsigned short ushort_t;
typedef __attribute__((ext_vector_type(8))) short   short8;
typedef __attribute__((ext_vector_type(4))) float   floatx4;
typedef __attribute__((ext_vector_type(4))) unsigned short ushort4v;

__device__ __forceinline__ ushort_t f2bf(float f) {
    union { float f; uint32_t u; } v; v.f = f;
    uint32_t r = v.u + 0x7fffu + ((v.u >> 16) & 1u);   // RNE
    return (ushort_t)(r >> 16);
}

__device__ __forceinline__ floatx4 mfma16(short8 a, short8 b, floatx4 c) {
    return __builtin_amdgcn_mfma_f32_16x16x32_bf16(a, b, c, 0, 0, 0);
}

// async global->LDS, 16B per lane; LDS dest is wave-uniform base + lane*16
__device__ __forceinline__ void gload16(const ushort_t* g, ushort_t* l) {
    __builtin_amdgcn_global_load_lds(
        (const __attribute__((address_space(1))) void*)g,
        (__attribute__((address_space(3))) void*)l, 16, 0, 0);
}

// decode padded-row tile id -> (expert, row0); returns 0 if past last tile
__device__ __forceinline__ int tile_decode(const int* __restrict__ counts,
                                           int tm, int& e_out, int& row0) {
    int cnts[NEXP];
#pragma unroll
    for (int e = 0; e < NEXP; ++e) cnts[e] = counts[e];   // independent loads
    int b = 0, t = tm;
#pragma unroll
    for (int e = 0; e < NEXP; ++e) {
        int nt = (cnts[e] + 127) >> 7;
        if (t < nt) { e_out = e; row0 = b + t * 128; return 1; }
        t -= nt; b += nt * 128;
    }
    return 0;
}

// ---------------------------------------------------------------- transpose+cvt (both weights, one dispatch)
// W1:[8][1024][4096] -> W1T:[8][4096][1024] bf16 ; W2:[8][4096][1024] -> W2T:[8][1024][4096] bf16
__global__ __launch_bounds__(256)
void transpose_all(const float* __restrict__ W1, const float* __restrict__ W2,
                   ushort_t* __restrict__ W1T, ushort_t* __restrict__ W2T)
{
    __shared__ float t[64][65];
    int bid = blockIdx.x;
    const float* in; ushort_t* out; int R, C, rt, ct;
    if (bid < 8192) {                       // W1 tiles: 16 r-tiles x 64 c-tiles per expert
        int e = bid >> 10, rem = bid & 1023;
        R = D_MODEL; C = D_FF; rt = rem >> 6; ct = rem & 63;
        in = W1 + (size_t)e * R * C; out = W1T + (size_t)e * R * C;
    } else {                                // W2 tiles: 64 r-tiles x 16 c-tiles per expert
        int e = (bid - 8192) >> 10, rem = bid & 1023;
        R = D_FF; C = D_MODEL; rt = rem >> 4; ct = rem & 15;
        in = W2 + (size_t)e * R * C; out = W2T + (size_t)e * R * C;
    }
    int r0 = rt * 64, c0 = ct * 64, tid = threadIdx.x;
    int lr = tid >> 4, lc4 = (tid & 15) * 4;
#pragma unroll
    for (int p = 0; p < 4; ++p) {
        int rr = p * 16 + lr;
        float4 v = *(const float4*)(in + (size_t)(r0 + rr) * C + c0 + lc4);
        t[rr][lc4] = v.x; t[rr][lc4 + 1] = v.y; t[rr][lc4 + 2] = v.z; t[rr][lc4 + 3] = v.w;
    }
    __syncthreads();
    int orw = tid >> 3, j0 = (tid & 7) * 8;
#pragma unroll
    for (int p = 0; p < 2; ++p) {
        int orow = p * 32 + orw;
        ushort_t pk[8];
#pragma unroll
        for (int i = 0; i < 8; ++i) pk[i] = f2bf(t[j0 + i][orow]);
        *(short8*)(out + (size_t)(c0 + orow) * R + r0 + j0) = *(short8*)pk;
    }
}

// ---------------------------------------------------------------- router (de-atomized)
// Wave-per-token GEMV. ZERO global atomics: top-2 per token -> top_e/top_pp,
// per-block softmax sums -> psum_part[block][8] (plain stores). Round-3 PMC
// showed the old single-kernel router at 197us with VALUBusy 3.5% / HBM 1.2%:
// pure same-address atomic serialization (16K counts + 16K psum RMWs on 16
// addresses ~ 2048 x ~75ns per chain). Slot allocation moved to assign_kernel.
__global__ __launch_bounds__(256)
void router_logits(const float* __restrict__ x, const float* __restrict__ Wg,
                   const float* __restrict__ bg,
                   int* __restrict__ top_e, float2* __restrict__ top_pp,
                   float* __restrict__ psum_part)
{
    __shared__ float bsum[NEXP];
    int tid = threadIdx.x;
    if (tid < NEXP) bsum[tid] = 0.f;
    __syncthreads();

    int t = (blockIdx.x * 256 + tid) >> 6;     // one wave per token
    int l = tid & 63;
    const float* xr = x + (size_t)t * D_MODEL;
    float acc[NEXP] = {0.f,0.f,0.f,0.f,0.f,0.f,0.f,0.f};
#pragma unroll 4
    for (int c = 0; c < D_MODEL / 64; ++c) {
        int d = c * 64 + l;
        float xv = xr[d];
        const float4* wr = (const float4*)(Wg + (size_t)d * NEXP);
        float4 w0 = wr[0], w1 = wr[1];
        acc[0] += xv * w0.x; acc[1] += xv * w0.y;
        acc[2] += xv * w0.z; acc[3] += xv * w0.w;
        acc[4] += xv * w1.x; acc[5] += xv * w1.y;
        acc[6] += xv * w1.z; acc[7] += xv * w1.w;
    }
#pragma unroll
    for (int off = 32; off >= 1; off >>= 1)
#pragma unroll
        for (int e = 0; e < NEXP; ++e)
            acc[e] += __shfl_xor(acc[e], off);

    if (l == 0) {
        float lg[NEXP], mx = -1e30f;
#pragma unroll
        for (int e = 0; e < NEXP; ++e) { lg[e] = acc[e] + bg[e]; mx = fmaxf(mx, lg[e]); }
        float pr[NEXP], s = 0.f;
#pragma unroll
        for (int e = 0; e < NEXP; ++e) { pr[e] = __expf(lg[e] - mx); s += pr[e]; }
        float inv = 1.f / s;
#pragma unroll
        for (int e = 0; e < NEXP; ++e) pr[e] *= inv;
        int e0 = 0;
#pragma unroll
        for (int e = 1; e < NEXP; ++e) if (pr[e] > pr[e0]) e0 = e;
        int e1 = (e0 == 0) ? 1 : 0;
#pragma unroll
        for (int e = 0; e < NEXP; ++e) if (e != e0 && pr[e] > pr[e1]) e1 = e;
        float pnorm = 1.f / (pr[e0] + pr[e1]);
        top_e[t] = e0 | (e1 << 8);
        top_pp[t] = make_float2(pr[e0] * pnorm, pr[e1] * pnorm);
#pragma unroll
        for (int e = 0; e < NEXP; ++e) atomicAdd(&bsum[e], pr[e]);  // LDS, 4 lanes/block
    }
    __syncthreads();
    if (tid < NEXP) psum_part[blockIdx.x * NEXP + tid] = bsum[tid];
}

// ---------------------------------------------------------------- assign (single block)
// Slot allocation via LDS atomics (16K RMWs on 8 LDS counters ~ 2-4us) +
// psum_part tree-reduce. Writes counts, slot_tok, slot_p, psum.
__global__ __launch_bounds__(256)
void assign_kernel(const int* __restrict__ top_e, const float2* __restrict__ top_pp,
                   const float* __restrict__ psum_part,
                   int* __restrict__ counts, int* __restrict__ slot_tok,
                   float* __restrict__ slot_p, float* __restrict__ psum)
{
    __shared__ int cnt[NEXP];
    __shared__ float red[256];
    int tid = threadIdx.x;
    if (tid < NEXP) cnt[tid] = 0;
    __syncthreads();
    for (int t = tid; t < NTOK; t += 256) {
        int ee = top_e[t];
        float2 pp = top_pp[t];
        int e0 = ee & 0xff, e1 = ee >> 8;
        int s0 = atomicAdd(&cnt[e0], 1);
        slot_tok[e0 * NTOK + s0] = t; slot_p[e0 * NTOK + s0] = pp.x;
        int s1 = atomicAdd(&cnt[e1], 1);
        slot_tok[e1 * NTOK + s1] = t; slot_p[e1 * NTOK + s1] = pp.y;
    }
    // psum reduce: thread tid handles expert e=tid&7, block-rows bi=tid>>3 step 32
    float acc = 0.f;
    int e = tid & 7, bi = tid >> 3;
    for (int b = bi; b < RBLK; b += 32)
        acc += psum_part[b * NEXP + e];
    red[tid] = acc;
    __syncthreads();                          // also drains the cnt atomics
    if (tid < NEXP) {
        float s = 0.f;
#pragma unroll
        for (int k = 0; k < 32; ++k) s += red[k * 8 + tid];
        psum[tid] = s;
        counts[tid] = cnt[tid];
    }
}

// ---------------------------------------------------------------- gather x -> xg (bf16)
__global__ __launch_bounds__(256)
void gather_kernel(const float* __restrict__ x, const int* __restrict__ counts,
                   const int* __restrict__ slot_tok, const float* __restrict__ slot_p,
                   ushort_t* __restrict__ xg, float* __restrict__ tok_prob,
                   int* __restrict__ tcount, int* __restrict__ tok2row)
{
    __shared__ int sb[NEXP + 1];
    int row = blockIdx.x, tid = threadIdx.x;
    if (tid == 0) {
        int b = 0;
#pragma unroll
        for (int e = 0; e < NEXP; ++e) { sb[e] = b; b += ((counts[e] + 127) >> 7) << 7; }
        sb[NEXP] = b;
    }
    __syncthreads();
    if (row >= sb[NEXP]) return;
    int e = 0;
    while (e < NEXP - 1 && row >= sb[e + 1]) ++e;
    int lr = row - sb[e];
    int tok = -1; float pr = 0.f;
    if (lr < counts[e]) { tok = slot_tok[e * NTOK + lr]; pr = slot_p[e * NTOK + lr]; }
    if (tid == 0) {
        tok_prob[row] = pr;
        if (tok >= 0) {
            int s = atomicAdd(&tcount[tok], 1);   // 0 or 1
            tok2row[tok * 2 + s] = row;
        }
    }
    ushort_t* dst = xg + (size_t)row * D_MODEL;
    if (tok >= 0) {
        float4 v = ((const float4*)(x + (size_t)tok * D_MODEL))[tid];
        ushort4v o; o.x = f2bf(v.x); o.y = f2bf(v.y); o.z = f2bf(v.z); o.w = f2bf(v.w);
        *(ushort4v*)(dst + tid * 4) = o;
    } else {
        *(ushort4v*)(dst + tid * 4) = ushort4v{0, 0, 0, 0};
    }
}

// ---------------------------------------------------------------- grouped GEMM
// C[128x128] = A[tile rows][K] * B[e][colbase..+128][K]^T  (both bf16, k-contig)
// 2-phase double-buffered pipeline (catalog T3-minimum + T4 counted vmcnt):
//   iter s: issue 8 global_load_lds -> buf[p^1]; s_waitcnt vmcnt(8) (waits
//   ONLY the previous tile's loads -- the new 8 stay in flight across the
//   barrier); raw s_barrier; MFMA on buf[p]; raw s_barrier.
// XOR chunk swizzle conflict-free via pre-swizzled global source (rule #21).
// XCD chunk swizzle (T1, bijective: nwg%8==0 for both grids) for L2 reuse
// (verified: FETCH 423->200 MB).
// EPI 0: h = relu(C + b1) -> bf16 Hout (single-barrier 32KB LDS epilogue)
// EPI 1: Yout[row] = C + b2 (f32, direct stores; combined later)
template <int EPI>
__global__ __launch_bounds__(256, 2)
void gemm_tile(const ushort_t* __restrict__ A, const ushort_t* __restrict__ B,
               int K, int N, const int* __restrict__ counts,
               int row_lo, int row_hi,
               ushort_t* __restrict__ Hout, const float* __restrict__ bias,
               float* __restrict__ Yout)
{
    // ---- XCD chunk (T1) then 4x4 super-tile: 16 consecutive = 4 cols x 4 tiles
    int NX = gridDim.x;
    int nwg = NX * (int)gridDim.y;           // 1088 or 4352, both %8==0
    int lin0 = blockIdx.y * NX + blockIdx.x;
    int cpx = nwg >> 3;
    int lin = (lin0 & 7) * cpx + (lin0 >> 3);
    int sid = lin >> 4, wi = lin & 15;
    int nsx = NX >> 2;
    int sx = sid % nsx, sy = sid / nsx;
    int colbase = ((sx << 2) + (wi & 3)) * 128;
    int tm = (sy << 2) + (wi >> 2);

    int e, row0;
    if (!tile_decode(counts, tm, e, row0)) return;
    if (row0 < row_lo || row0 >= row_hi) return;

    // double buffer: buf p at smem + p*16384 elems (As 16KB | Bs 16KB each)
    __shared__ ushort_t smem[128 * 64 * 2 * 2];  // 64 KB

    int tid = threadIdx.x;
    int w = tid >> 6, l = tid & 63;
    int q = l >> 4, ml = l & 15;
    int wm = w >> 1, wn = w & 1;

    const ushort_t* Ab = A + (size_t)row0 * K;
    const ushort_t* Bb = B + ((size_t)e * N + colbase) * K;

    // staging geometry: issue i of wave w covers LDS rows [(i*4+w)*8, +8)
    // linearly (1KB). LDS (r, chunk c) must hold global chunk (c ^ (r&7)).
    const ushort_t* ag[4]; const ushort_t* bg[4];
    int lofs[4];
#pragma unroll
    for (int i = 0; i < 4; ++i) {
        int rr = (i * 4 + w) * 8 + (l >> 3);
        int cc = ((l & 7) ^ (rr & 7)) * 8;       // pre-swizzled source chunk
        ag[i] = Ab + (size_t)rr * K + cc;
        bg[i] = Bb + (size_t)rr * K + cc;
        lofs[i] = (i * 4 + w) * 512;             // wave-uniform dest base (elems)
    }

#define STAGE(p)                                                           \
    do {                                                                   \
        ushort_t* base_ = smem + (p) * 16384;                              \
        _Pragma("unroll")                                                  \
        for (int i_ = 0; i_ < 4; ++i_) {                                   \
            gload16(ag[i_], base_ + lofs[i_]);                             \
            gload16(bg[i_], base_ + 8192 + lofs[i_]);                      \
            ag[i_] += 64; bg[i_] += 64;                                    \
        }                                                                  \
    } while (0)

    floatx4 acc[4][4];
#pragma unroll
    for (int i = 0; i < 4; ++i)
#pragma unroll
        for (int j = 0; j < 4; ++j) acc[i][j] = floatx4{0.f, 0.f, 0.f, 0.f};

    int nst = K >> 6;
    STAGE(0);                                    // prologue: tile 0 in flight
    for (int s = 0; s < nst; ++s) {
        int p = s & 1;
        if (s + 1 < nst) {
            STAGE(p ^ 1);                        // next tile: stays in flight
            asm volatile("s_waitcnt vmcnt(8)" ::: "memory");   // prev 8 done
        } else {
            asm volatile("s_waitcnt vmcnt(0)" ::: "memory");
        }
        __builtin_amdgcn_s_barrier();            // buf[p] collectively ready
        __builtin_amdgcn_sched_barrier(0);       // keep ds_reads below waits
        const ushort_t* As = smem + p * 16384;
        const ushort_t* Bs = As + 8192;
#pragma unroll
        for (int kk = 0; kk < 2; ++kk) {
            int cb = kk * 4 + q;
            short8 av[4], bv[4];
#pragma unroll
            for (int mi = 0; mi < 4; ++mi) {
                int m = wm * 64 + mi * 16 + ml;
                av[mi] = *(const short8*)(As + m * 64 + ((cb ^ (m & 7)) * 8));
            }
#pragma unroll
            for (int ni = 0; ni < 4; ++ni) {
                int n = wn * 64 + ni * 16 + ml;
                bv[ni] = *(const short8*)(Bs + n * 64 + ((cb ^ (n & 7)) * 8));
            }
#pragma unroll
            for (int mi = 0; mi < 4; ++mi)
#pragma unroll
                for (int ni = 0; ni < 4; ++ni)
                    acc[mi][ni] = mfma16(av[mi], bv[ni], acc[mi][ni]);
        }
        __builtin_amdgcn_s_barrier();            // reads done before overwrite
    }
#undef STAGE

    float bv4[4];
#pragma unroll
    for (int ni = 0; ni < 4; ++ni)
        bv4[ni] = bias[e * N + colbase + wn * 64 + ni * 16 + ml];

    if (EPI == 0) {
        // single-barrier epilogue: full 128x128 bf16 tile in smem buf0
        ushort_t* ct = smem;
#pragma unroll
        for (int mi = 0; mi < 4; ++mi)
#pragma unroll
            for (int ni = 0; ni < 4; ++ni)
#pragma unroll
                for (int r = 0; r < 4; ++r) {
                    float v = acc[mi][ni][r] + bv4[ni];
                    v = v > 0.f ? v : 0.f;
                    ct[(wm * 64 + mi * 16 + q * 4 + r) * 128 + wn * 64 + ni * 16 + ml] = f2bf(v);
                }
        __syncthreads();
#pragma unroll
        for (int i = 0; i < 8; ++i) {
            int idx = tid + i * 256;             // 2048 chunks of 16B
            int r = idx >> 4, c8 = idx & 15;
            *(short8*)(Hout + (size_t)(row0 + r) * D_FF + colbase + c8 * 8) =
                *(const short8*)(ct + r * 128 + c8 * 8);
        }
    } else {
#pragma unroll
        for (int mi = 0; mi < 4; ++mi)
#pragma unroll
            for (int ni = 0; ni < 4; ++ni)
#pragma unroll
                for (int r = 0; r < 4; ++r) {
                    int row = row0 + wm * 64 + mi * 16 + q * 4 + r;
                    int col = colbase + wn * 64 + ni * 16 + ml;
                    Yout[(size_t)row * N + col] = acc[mi][ni][r] + bv4[ni];
                }
    }
}

// ---------------------------------------------------------------- combine (+loss)
__global__ __launch_bounds__(256)
void combine_kernel(const float* __restrict__ y, const int* __restrict__ tok2row,
                    const float* __restrict__ tok_prob, float* __restrict__ out,
                    const float* __restrict__ psum, float* __restrict__ loss_out)
{
    int t = blockIdx.x;
    if (t == 0 && threadIdx.x == 0) {
        float me[NEXP], m = 0.f;
#pragma unroll
        for (int e = 0; e < NEXP; ++e) { me[e] = psum[e] * (1.f / NTOK); m += me[e] * (1.f / NEXP); }
        float v = 0.f;
#pragma unroll
        for (int e = 0; e < NEXP; ++e) v += (me[e] - m) * (me[e] - m);
        loss_out[0] = v * (1.f / (NEXP - 1));
    }
    int r0 = tok2row[t * 2], r1 = tok2row[t * 2 + 1];
    float p0 = tok_prob[r0], p1 = tok_prob[r1];
    int c = threadIdx.x;
    float4 a = ((const float4*)(y + (size_t)r0 * D_MODEL))[c];
    float4 b = ((const float4*)(y + (size_t)r1 * D_MODEL))[c];
    float4 o;
    o.x = p0 * a.x + p1 * b.x;
    o.y = p0 * a.y + p1 * b.y;
    o.z = p0 * a.z + p1 * b.z;
    o.w = p0 * a.w + p1 * b.w;
    ((float4*)(out + (size_t)t * D_MODEL))[c] = o;
}

// ---------------------------------------------------------------- launch
extern "C" void kernel_launch(void* const* d_in, const int* in_sizes, int n_in,
                              void* d_out, int out_size, void* d_ws, size_t ws_size,
                              hipStream_t stream)
{
    const float* x  = (const float*)d_in[0];
    const float* Wg = (const float*)d_in[1];
    const float* bg = (const float*)d_in[2];
    const float* W1 = (const float*)d_in[3];
    const float* b1 = (const float*)d_in[4];
    const float* W2 = (const float*)d_in[5];
    const float* b2 = (const float*)d_in[6];
    float* out = (float*)d_out;

    char* ws = (char*)d_ws;
    size_t off = 0;
    auto alloc = [&](size_t bytes) -> char* {
        char* p = ws + off;
        off = (off + bytes + 255) & ~(size_t)255;
        return p;
    };
    // zero-initialized region first (one memset covers it)
    int*      counts   = (int*)alloc(NEXP * 4);
    float*    psum     = (float*)alloc(NEXP * 4);
    int*      tcount   = (int*)alloc(NTOK * 4);
    size_t zero_bytes = off;
    // rest
    float*    tok_prob = (float*)alloc(CAP * 4);
    int*      tok2row  = (int*)alloc((size_t)NTOK * 2 * 4);
    int*      slot_tok = (int*)alloc((size_t)NEXP * NTOK * 4);
    float*    slot_p   = (float*)alloc((size_t)NEXP * NTOK * 4);
    int*      top_e    = (int*)alloc((size_t)NTOK * 4);
    float2*   top_pp   = (float2*)alloc((size_t)NTOK * 8);
    float*    psum_part= (float*)alloc((size_t)RBLK * NEXP * 4);
    ushort_t* xg       = (ushort_t*)alloc((size_t)CAP * D_MODEL * 2);
    ushort_t* W1T      = (ushort_t*)alloc((size_t)NEXP * D_MODEL * D_FF * 2);
    ushort_t* W2T      = (ushort_t*)alloc((size_t)NEXP * D_MODEL * D_FF * 2);
    float*    ybuf     = (float*)alloc((size_t)CAP * D_MODEL * 4);
    size_t fixed = off;
    size_t h_full = (size_t)CAP * D_FF * 2;

    int NC = 1;                                    // chunk h if ws is small
    if (ws_size < fixed + h_full) NC = 4;
    if (NC == 4 && ws_size < fixed + h_full / 4) NC = 16;
    if (ws_size < fixed + h_full / NC) return;     // cannot run safely
    int chunk_rows = CAP / NC;
    ushort_t* hbuf = (ushort_t*)alloc(h_full / NC);

    hipMemsetAsync(d_ws, 0, zero_bytes, stream);   // counts + psum + tcount

    transpose_all<<<16384, 256, 0, stream>>>(W1, W2, W1T, W2T);
    router_logits<<<RBLK, 256, 0, stream>>>(x, Wg, bg, top_e, top_pp, psum_part);
    assign_kernel<<<1, 256, 0, stream>>>(top_e, top_pp, psum_part,
                                         counts, slot_tok, slot_p, psum);
    gather_kernel<<<CAP, 256, 0, stream>>>(x, counts, slot_tok, slot_p, xg,
                                           tok_prob, tcount, tok2row);
    for (int c = 0; c < NC; ++c) {
        int lo = c * chunk_rows, hi = lo + chunk_rows;
        ushort_t* h_eff = hbuf - (ptrdiff_t)lo * D_FF;   // abs-row indexed view
        gemm_tile<0><<<dim3(D_FF / 128, MAXT), 256, 0, stream>>>(
            xg, W1T, D_MODEL, D_FF, counts, lo, hi, h_eff, b1, nullptr);
        gemm_tile<1><<<dim3(D_MODEL / 128, MAXT), 256, 0, stream>>>(
            h_eff, W2T, D_FF, D_MODEL, counts, lo, hi, nullptr, b2, ybuf);
    }
    combine_kernel<<<NTOK, 256, 0, stream>>>(ybuf, tok2row, tok_prob, out, psum,
                                             out + (size_t)out_size - 1);
    (void)in_sizes; (void)n_in;
}